// Round 5
// baseline (436.478 us; speedup 1.0000x reference)
//
#include <hip/hip_runtime.h>

// CapsuleLayer dynamic routing, MI355X. R8: 4 blocks/CU occupancy push.
//  - R3..R7 post-mortem: every variant runs <=8 waves/CU (grid cap) with
//    VALUBusy<=25%, HBM<=18%, occ 13-20% -> wave-starved latency stalls.
//  - This version keeps R5's proven hot loop (4b/wave, SGPR x upfront,
//    2x ds_read_b128 -> 32 FMA per k) and raises concurrency:
//    grid 1024 = 512 ig (IC=4) x 2 bh, SINGLE 32KB LDS buffer ->
//    4 blocks/CU (128KB LDS), 16 waves/CU. __launch_bounds__(256,4) caps
//    VGPR at 128 (PASS2 ~100 live with the as=a0+a1 fold -> no spill).
//  - Single-buffer glds staging: barrier(ready) -> compute -> barrier(done)
//    -> issue glds next. Within-block drain is exposed, but 4 phase-offset
//    blocks/CU cover each other.
//  - Cost: partial = 33.5MB (NG=512). Bet: sweep stall reduction >> +15us
//    of extra partial traffic in reduces.
//
// Lane layout: lane l owns d = l>>1, h = l&1, outputs o = d*16 + h*8 + j
// (j=0..7).  a-half combine: shfl_xor(.,1); softmax over D: shfl_xor
// {2,4,8,16,32}.  x loaded upfront per ii as wave-uniform scalar loads.
// LDS W layout: sW[jq*4096 + k*256 + (d*2+h)*4 + (j&3)]; staged via
// global_load_lds dwordx4 with pre-swizzled source addresses.

#define B_  32
#define I_  2048
#define K_  16
#define O_  512
#define NG_ 512   // i-groups (partial-buffer leading dim)
#define IC_ 4     // i's per group

#define GLB(p)  ((const __attribute__((address_space(1))) void*)(p))
#define LDSP(p) ((__attribute__((address_space(3))) void*)(p))

template<int PASS>
__global__ __launch_bounds__(256, 4)
void sweep_kernel(const float* __restrict__ x, const float* __restrict__ W,
                  const float* __restrict__ act0_g, const float* __restrict__ act1_g,
                  float* __restrict__ partial)
{
    const int tid  = threadIdx.x;
    const int lane = tid & 63;
    const int wave = tid >> 6;              // 0..3
    const int bid  = blockIdx.x;            // 0..1023
    // XCD-pair swizzle: xcd = bid&7 round-robin; bh-pair differs in bit 3
    // (same XCD -> second block's W reads hit that XCD's L2)
    const int ig   = (bid & 7) * 64 + (bid >> 4);   // 0..511
    const int bh   = (bid >> 3) & 1;                 // batch half
    const int d    = lane >> 1;             // 0..31
    const int h    = lane & 1;
    const int obase = d * 16 + h * 8;       // lane's first o

    // wave-uniform batch base (forces SGPR so x loads go scalar)
    const int wv    = __builtin_amdgcn_readfirstlane(wave);
    const int bbase = bh * 16 + wv * 4;

    __shared__ float sW[K_ * O_];           // 32 KB, permuted W[i] tile

    // per-lane pre-swizzled source byte offsets: slot s -> global float4 f
    // s = 1024*jq + 64*k + (2*dd+hh); bijection verified on [0,2048)
    int voff[8];
    #pragma unroll
    for (int c = 0; c < 8; ++c) {
        const int s = c * 256 + wave * 64 + lane;       // 16B slot index
        const int f = ((s >> 10) & 1) | ((s & 1) << 1)
                    | (((s >> 1) & 31) << 2) | (((s >> 6) & 15) << 7);
        voff[c] = f << 4;                               // byte offset
    }

    float facc[4][8];
    #pragma unroll
    for (int bb = 0; bb < 4; ++bb)
        #pragma unroll
        for (int j = 0; j < 8; ++j) facc[bb][j] = 0.f;

    // as_ = a0 (PASS1) or a0+a1 (PASS2): round-2 logits = V.(a0+a1)
    float as_[4][8];
    if (PASS >= 1) {
        #pragma unroll
        for (int bb = 0; bb < 4; ++bb) {
            const float4* p = (const float4*)(act0_g + (bbase + bb) * O_ + obase);
            float4 f0 = p[0], f1 = p[1];
            as_[bb][0]=f0.x; as_[bb][1]=f0.y; as_[bb][2]=f0.z; as_[bb][3]=f0.w;
            as_[bb][4]=f1.x; as_[bb][5]=f1.y; as_[bb][6]=f1.z; as_[bb][7]=f1.w;
            if (PASS == 2) {
                const float4* q = (const float4*)(act1_g + (bbase + bb) * O_ + obase);
                float4 g0 = q[0], g1 = q[1];
                as_[bb][0]+=g0.x; as_[bb][1]+=g0.y; as_[bb][2]+=g0.z; as_[bb][3]+=g0.w;
                as_[bb][4]+=g1.x; as_[bb][5]+=g1.y; as_[bb][6]+=g1.z; as_[bb][7]+=g1.w;
            }
        }
    }

    // prologue: stage W[i0]
    {
        const char* gb = (const char*)(W + (size_t)(ig * IC_) * (K_ * O_));
        #pragma unroll
        for (int c = 0; c < 8; ++c)
            __builtin_amdgcn_global_load_lds(GLB(gb + voff[c]),
                LDSP(&sW[(c * 256 + wave * 64) * 4]), 16, 0, 0);
    }

    #pragma unroll 1
    for (int ii = 0; ii < IC_; ++ii) {
        const int i = ig * IC_ + ii;

        // x for this wave's 4 b's: wave-uniform scalar loads, issued before
        // the barrier so s_load latency overlaps the barrier wait
        float xs[4][16];
        #pragma unroll
        for (int bb = 0; bb < 4; ++bb) {
            const float4* xp = (const float4*)(x + ((size_t)(bbase + bb) * I_ + i) * K_);
            #pragma unroll
            for (int q = 0; q < 4; ++q) {
                float4 v = xp[q];
                xs[bb][4*q+0]=v.x; xs[bb][4*q+1]=v.y; xs[bb][4*q+2]=v.z; xs[bb][4*q+3]=v.w;
            }
        }

        // implicit vmcnt(0) + barrier: tile ii fully staged
        __syncthreads();

        // V[bb][j]: 2 ds_read_b128 per k feeding 32 FMA
        float V[4][8];
        #pragma unroll
        for (int bb = 0; bb < 4; ++bb)
            #pragma unroll
            for (int j = 0; j < 8; ++j) V[bb][j] = 0.f;
        #pragma unroll
        for (int k = 0; k < K_; ++k) {
            const float4 w0 = *(const float4*)&sW[k * 256 + lane * 4];
            const float4 w1 = *(const float4*)&sW[4096 + k * 256 + lane * 4];
            const float w[8] = {w0.x, w0.y, w0.z, w0.w, w1.x, w1.y, w1.z, w1.w};
            #pragma unroll
            for (int bb = 0; bb < 4; ++bb) {
                const float xb = xs[bb][k];
                #pragma unroll
                for (int j = 0; j < 8; ++j) V[bb][j] = fmaf(xb, w[j], V[bb][j]);
            }
        }

        // all waves done reading sW -> restage for next i
        if (ii + 1 < IC_) {
            __syncthreads();
            const char* gb = (const char*)(W + (size_t)(i + 1) * (K_ * O_));
            #pragma unroll
            for (int c = 0; c < 8; ++c)
                __builtin_amdgcn_global_load_lds(GLB(gb + voff[c]),
                    LDSP(&sW[(c * 256 + wave * 64) * 4]), 16, 0, 0);
        }

        #pragma unroll
        for (int bb = 0; bb < 4; ++bb) {
            if (PASS == 0) {
                #pragma unroll
                for (int j = 0; j < 8; ++j) facc[bb][j] += V[bb][j];
            } else {
                float p0 = 0.f;
                #pragma unroll
                for (int j = 0; j < 8; ++j) p0 = fmaf(V[bb][j], as_[bb][j], p0);
                p0 += __shfl_xor(p0, 1);        // combine the two a-halves
                // softmax over 32 d's (no max-sub: |logits| small, f32-safe)
                const float e = __expf(p0);
                float s = e;
                s += __shfl_xor(s, 2);
                s += __shfl_xor(s, 4);
                s += __shfl_xor(s, 8);
                s += __shfl_xor(s, 16);
                s += __shfl_xor(s, 32);
                const float r = e * __builtin_amdgcn_rcpf(s);
                #pragma unroll
                for (int j = 0; j < 8; ++j)
                    facc[bb][j] = fmaf(r, V[bb][j], facc[bb][j]);
            }
        }
    }

    // flush per-(ig) partials
    #pragma unroll
    for (int bb = 0; bb < 4; ++bb) {
        const int b = bbase + bb;
        float4* dst = (float4*)(partial + ((size_t)ig * B_ + b) * O_ + obase);
        dst[0] = make_float4(facc[bb][0], facc[bb][1], facc[bb][2], facc[bb][3]);
        dst[1] = make_float4(facc[bb][4], facc[bb][5], facc[bb][6], facc[bb][7]);
    }
}

// sum NG_ partials -> *scale + bias -> squash over A -> out
// 512 wgs x 256 thr; wg covers 32 g's; 8 w-slices of 64 reduced via LDS.
__global__ __launch_bounds__(256)
void reduce_squash(const float* __restrict__ partial, const float* __restrict__ bias,
                   float scale, float* __restrict__ out)
{
    const int t  = threadIdx.x;
    const int g  = blockIdx.x * 32 + (t & 31);   // b*512 + o
    const int sl = t >> 5;                       // w-slice 0..7
    float s = 0.f;
    #pragma unroll 8
    for (int w = sl * 64; w < sl * 64 + 64; ++w)
        s += partial[(size_t)w * (B_ * O_) + g];
    __shared__ float red[256];
    red[t] = s;
    __syncthreads();
    if (t < 32) {
        float v = red[t];
        #pragma unroll
        for (int r = 1; r < 8; ++r) v += red[t + 32 * r];
        const float p = fmaf(v, scale, bias[g & (O_ - 1)]);
        float nn = p * p;
        nn += __shfl_xor(nn, 1);
        nn += __shfl_xor(nn, 2);
        nn += __shfl_xor(nn, 4);
        nn += __shfl_xor(nn, 8);
        out[g] = p * sqrtf(nn) / (1.f + nn);
    }
}

extern "C" void kernel_launch(void* const* d_in, const int* in_sizes, int n_in,
                              void* d_out, int out_size, void* d_ws, size_t ws_size,
                              hipStream_t stream) {
    const float* x    = (const float*)d_in[0];   // [32,2048,16]
    const float* W    = (const float*)d_in[1];   // [2048,16,512]
    const float* bias = (const float*)d_in[2];   // [512]
    float* out = (float*)d_out;                  // [32,512]

    float* partial = (float*)d_ws;                       // NG_*32*512 f32 = 33.5 MB
    float* act0    = partial + (size_t)NG_ * B_ * O_;    // 64 KB
    float* act1    = act0 + B_ * O_;                     // 64 KB

    sweep_kernel<0><<<NG_ * 2, 256, 0, stream>>>(x, W, nullptr, nullptr, partial);
    reduce_squash<<<512, 256, 0, stream>>>(partial, bias, 1.f / 32.f, act0);
    sweep_kernel<1><<<NG_ * 2, 256, 0, stream>>>(x, W, act0, nullptr, partial);
    reduce_squash<<<512, 256, 0, stream>>>(partial, bias, 1.f, act1);
    sweep_kernel<2><<<NG_ * 2, 256, 0, stream>>>(x, W, act0, act1, partial);
    reduce_squash<<<512, 256, 0, stream>>>(partial, bias, 1.f, out);
}

// Round 6
// 217.559 us; speedup vs baseline: 2.0062x; 2.0062x over previous
//
#include <hip/hip_runtime.h>

// CapsuleLayer dynamic routing, MI355X. R9: materialize votes, stream rounds.
//  - R3..R8: every "recompute votes per round" variant stalled at 50-85us per
//    sweep with NO pipe busy (VALU<=25%, HBM<=18%, conflicts 0) -> the
//    barrier-coupled stage->compute structure is the bottleneck, not a pipe.
//  - R9 materializes votes[i][b][o] (134MB ws) ONCE with an embarrassingly
//    parallel kernel (block per i, one barrier, no loop over tiles), then all
//    3 routing rounds are pure streaming kernels with zero barriers/LDS:
//      round0 = float4 reduction over i of votes (nw=2048 reduce_squash)
//      round1/2 = route_kernel: per-(b,i)-row dot + softmax + accumulate
//    Streaming reads/writes with 8 blocks/CU is the 6.3TB/s regime (m13).
//  - Round-2 logits fold: logits2 = votes.(act0+act1)  (logits accumulate).
//
// votes_kernel lane layout: wave owns 4 b's, lane owns o = [8*lane, 8*lane+8)
// via permuted LDS W tile (slot s = jq*1024+k*64+(dd*2+hh) <-> global float4
// f = k*128+dd*4+hh*2+jq, staged by global_load_lds with pre-swizzled source).
// route_kernel: lane owns same 8 o's; d = lane>>1, h = lane&1;
// h-combine shfl_xor(1), softmax over 32 d's shfl_xor {2,4,8,16,32}.

#define B_  32
#define I_  2048
#define K_  16
#define O_  512

#define GLB(p)  ((const __attribute__((address_space(1))) void*)(p))
#define LDSP(p) ((__attribute__((address_space(3))) void*)(p))

// ---------------------------------------------------------------- votes ----
// one block per i: 512 thr = 8 waves x 4 b. Stage W[i] (32KB) once, k-loop,
// write votes[i][b][o]. No tile loop -> single barrier, fully parallel grid.
__global__ __launch_bounds__(512)
void votes_kernel(const float* __restrict__ x, const float* __restrict__ W,
                  float* __restrict__ votes)
{
    const int tid  = threadIdx.x;
    const int lane = tid & 63;
    const int wave = tid >> 6;              // 0..7
    const int i    = blockIdx.x;            // 0..2047

    // wave-uniform batch base (forces SGPR so x loads go scalar)
    const int wv    = __builtin_amdgcn_readfirstlane(wave);
    const int bbase = wv * 4;               // 8 waves x 4 b = 32 b

    __shared__ float sW[K_ * O_];           // 32 KB permuted W[i]

    // stage: 2048 slots / 512 thr = 4 glds dwordx4 per thread,
    // pre-swizzled source (slot<->float4 bijection verified on [0,2048))
    {
        const char* gb = (const char*)(W + (size_t)i * (K_ * O_));
        #pragma unroll
        for (int c = 0; c < 4; ++c) {
            const int s = c * 512 + tid;    // 16B slot index
            const int f = ((s >> 10) & 1) | ((s & 1) << 1)
                        | (((s >> 1) & 31) << 2) | (((s >> 6) & 15) << 7);
            __builtin_amdgcn_global_load_lds(GLB(gb + (f << 4)),
                LDSP(&sW[(c * 512 + wave * 64) * 4]), 16, 0, 0);
        }
    }

    // x for this wave's 4 b's: wave-uniform scalar loads
    float xs[4][16];
    #pragma unroll
    for (int bb = 0; bb < 4; ++bb) {
        const float4* xp = (const float4*)(x + ((size_t)(bbase + bb) * I_ + i) * K_);
        #pragma unroll
        for (int q = 0; q < 4; ++q) {
            float4 v = xp[q];
            xs[bb][4*q+0]=v.x; xs[bb][4*q+1]=v.y; xs[bb][4*q+2]=v.z; xs[bb][4*q+3]=v.w;
        }
    }

    __syncthreads();   // implicit vmcnt(0): tile staged

    float V[4][8];
    #pragma unroll
    for (int bb = 0; bb < 4; ++bb)
        #pragma unroll
        for (int j = 0; j < 8; ++j) V[bb][j] = 0.f;
    #pragma unroll
    for (int k = 0; k < K_; ++k) {
        const float4 w0 = *(const float4*)&sW[k * 256 + lane * 4];
        const float4 w1 = *(const float4*)&sW[4096 + k * 256 + lane * 4];
        const float w[8] = {w0.x, w0.y, w0.z, w0.w, w1.x, w1.y, w1.z, w1.w};
        #pragma unroll
        for (int bb = 0; bb < 4; ++bb) {
            const float xb = xs[bb][k];
            #pragma unroll
            for (int j = 0; j < 8; ++j) V[bb][j] = fmaf(xb, w[j], V[bb][j]);
        }
    }

    // write votes[i][b][o]; lane covers o = [8*lane, 8*lane+8)
    #pragma unroll
    for (int bb = 0; bb < 4; ++bb) {
        float4* dst = (float4*)(votes + ((size_t)i * B_ + bbase + bb) * O_ + lane * 8);
        dst[0] = make_float4(V[bb][0], V[bb][1], V[bb][2], V[bb][3]);
        dst[1] = make_float4(V[bb][4], V[bb][5], V[bb][6], V[bb][7]);
    }
}

// ---------------------------------------------------------------- route ----
// rounds 1/2: grid 2048 = 64 ichunks x 32 b; 256 thr = 4 waves x 8 i.
// Zero barriers, zero LDS: per i-row, 2 coalesced dwordx4 loads of votes,
// dot with as_, h-combine, softmax over d, accumulate r*V.
// PASS=1: as_=act0 ; PASS=2: as_=act0+act1 (logits accumulate across rounds).
template<int PASS>
__global__ __launch_bounds__(256)
void route_kernel(const float* __restrict__ votes, const float* __restrict__ act0,
                  const float* __restrict__ act1, float* __restrict__ partial)
{
    const int tid  = threadIdx.x;
    const int lane = tid & 63;
    const int wave = tid >> 6;              // 0..3
    const int b    = blockIdx.x & 31;
    const int ic   = blockIdx.x >> 5;       // 0..63
    const int i0   = ic * 32 + wave * 8;

    // lane's 8 o's = [8*lane, 8*lane+8)
    float as_[8];
    {
        const float4* p = (const float4*)(act0 + b * O_ + lane * 8);
        float4 f0 = p[0], f1 = p[1];
        as_[0]=f0.x; as_[1]=f0.y; as_[2]=f0.z; as_[3]=f0.w;
        as_[4]=f1.x; as_[5]=f1.y; as_[6]=f1.z; as_[7]=f1.w;
        if (PASS == 2) {
            const float4* q = (const float4*)(act1 + b * O_ + lane * 8);
            float4 g0 = q[0], g1 = q[1];
            as_[0]+=g0.x; as_[1]+=g0.y; as_[2]+=g0.z; as_[3]+=g0.w;
            as_[4]+=g1.x; as_[5]+=g1.y; as_[6]+=g1.z; as_[7]+=g1.w;
        }
    }

    float facc[8];
    #pragma unroll
    for (int j = 0; j < 8; ++j) facc[j] = 0.f;

    #pragma unroll
    for (int ii = 0; ii < 8; ++ii) {
        const float4* vp = (const float4*)(votes + ((size_t)(i0 + ii) * B_ + b) * O_ + lane * 8);
        const float4 v0 = vp[0], v1 = vp[1];
        const float V[8] = {v0.x, v0.y, v0.z, v0.w, v1.x, v1.y, v1.z, v1.w};
        float p0 = 0.f;
        #pragma unroll
        for (int j = 0; j < 8; ++j) p0 = fmaf(V[j], as_[j], p0);
        p0 += __shfl_xor(p0, 1);            // combine the two a-halves
        // softmax over 32 d's (no max-sub: |logits| small, f32-safe)
        const float e = __expf(p0);
        float s = e;
        s += __shfl_xor(s, 2);
        s += __shfl_xor(s, 4);
        s += __shfl_xor(s, 8);
        s += __shfl_xor(s, 16);
        s += __shfl_xor(s, 32);
        const float r = e * __builtin_amdgcn_rcpf(s);
        #pragma unroll
        for (int j = 0; j < 8; ++j) facc[j] = fmaf(r, V[j], facc[j]);
    }

    // partial[ic*4+wave][b][o]
    float4* dst = (float4*)(partial + ((size_t)(ic * 4 + wave) * B_ + b) * O_ + lane * 8);
    dst[0] = make_float4(facc[0], facc[1], facc[2], facc[3]);
    dst[1] = make_float4(facc[4], facc[5], facc[6], facc[7]);
}

// --------------------------------------------------------------- reduce ----
// sum nw partials (layout [nw][B][O] = [nw][4096] float4) -> *scale + bias
// -> squash over A -> out.  grid 512 x 256: block covers 8 float4-columns,
// 32 w-slices reduced via LDS. Coalesced float4 reads (8 lanes = 128B segs).
__global__ __launch_bounds__(256)
void reduce_squash(const float* __restrict__ partial, const float* __restrict__ bias,
                   float scale, int nw, float* __restrict__ out)
{
    const int t   = threadIdx.x;
    const int g4  = blockIdx.x * 8 + (t & 7);    // float4 column, 0..4095
    const int sl  = t >> 3;                      // w-slice 0..31
    const int per = nw >> 5;                     // nw/32
    const float4* p4 = (const float4*)partial;
    float4 s = make_float4(0.f, 0.f, 0.f, 0.f);
    #pragma unroll 8
    for (int w = sl * per; w < sl * per + per; ++w) {
        const float4 v = p4[(size_t)w * (B_ * O_ / 4) + g4];
        s.x += v.x; s.y += v.y; s.z += v.z; s.w += v.w;
    }
    __shared__ float4 red[256];
    red[t] = s;
    __syncthreads();
    if (t < 8) {
        float4 v = red[t];
        #pragma unroll
        for (int r = 1; r < 32; ++r) {
            const float4 u = red[t + 8 * r];
            v.x += u.x; v.y += u.y; v.z += u.z; v.w += u.w;
        }
        const float4 bi = ((const float4*)bias)[g4 & 127];
        float4 p;
        p.x = fmaf(v.x, scale, bi.x);
        p.y = fmaf(v.y, scale, bi.y);
        p.z = fmaf(v.z, scale, bi.z);
        p.w = fmaf(v.w, scale, bi.w);
        float nn = p.x*p.x + p.y*p.y + p.z*p.z + p.w*p.w;
        nn += __shfl_xor(nn, 1);     // 4 threads (16 a's) share one d
        nn += __shfl_xor(nn, 2);
        const float sc = sqrtf(nn) / (1.f + nn);
        p.x *= sc; p.y *= sc; p.z *= sc; p.w *= sc;
        ((float4*)out)[g4] = p;
    }
}

extern "C" void kernel_launch(void* const* d_in, const int* in_sizes, int n_in,
                              void* d_out, int out_size, void* d_ws, size_t ws_size,
                              hipStream_t stream) {
    const float* x    = (const float*)d_in[0];   // [32,2048,16]
    const float* W    = (const float*)d_in[1];   // [2048,16,512]
    const float* bias = (const float*)d_in[2];   // [512]
    float* out = (float*)d_out;                  // [32,512]

    float* votes   = (float*)d_ws;                       // 2048*32*512 f32 = 134.2 MB
    float* partial = votes + (size_t)I_ * B_ * O_;       // 256*32*512 f32 = 16.8 MB
    float* act0    = partial + (size_t)256 * B_ * O_;    // 64 KB
    float* act1    = act0 + B_ * O_;                     // 64 KB

    votes_kernel<<<I_, 512, 0, stream>>>(x, W, votes);
    reduce_squash<<<512, 256, 0, stream>>>(votes, bias, 1.f / 32.f, I_, act0);
    route_kernel<1><<<2048, 256, 0, stream>>>(votes, act0, nullptr, partial);
    reduce_squash<<<512, 256, 0, stream>>>(partial, bias, 1.f, 256, act1);
    route_kernel<2><<<2048, 256, 0, stream>>>(votes, act0, act1, partial);
    reduce_squash<<<512, 256, 0, stream>>>(partial, bias, 1.f, 256, out);
}